// Round 1
// 540.965 us; speedup vs baseline: 1.0140x; 1.0140x over previous
//
#include <hip/hip_runtime.h>

// Problem: out[n,:] = concat(x[n,:], mean[batch_id[n],:]) @ W^T + b
//   N ~= 500000 nodes, IN = 128, OUT = 128, G = 1024 graphs, batch_id SORTED.
// Decomposition: out = x @ W1^T + ctx[batch_id], ctx[g] = mean[g] @ W2^T + b.
// This version: pass1 (mean+ctx) ALSO restages x as bf16 into workspace (xb)
// and converts W1 -> bf16; the GEMM then reads bf16 (half the bytes, L3-hot,
// no f2bf packing on the critical path) with 3 blocks/CU occupancy.

#define G_NUM 1024
#define IN_F 128
#define OUT_F 128

typedef __attribute__((ext_vector_type(8))) short short8;          // 8 bf16 = 4 VGPRs
typedef __attribute__((ext_vector_type(4))) float f32x4;           // MFMA C/D frag
typedef __attribute__((ext_vector_type(4))) unsigned short us4;    // 4 bf16 = 8B store

static __device__ __forceinline__ unsigned short f2bf(float f) {
    union { float f; unsigned u; } v; v.f = f;
    unsigned u = v.u;
    return (unsigned short)((u + 0x7FFFu + ((u >> 16) & 1u)) >> 16);  // RNE
}

static __device__ __forceinline__ us4 pack4(float4 a) {
    us4 o;
    o[0] = f2bf(a.x); o[1] = f2bf(a.y); o[2] = f2bf(a.z); o[3] = f2bf(a.w);
    return o;
}

static __device__ __forceinline__ short8 pack8(float4 a, float4 b) {
    short8 o;
    o[0] = (short)f2bf(a.x); o[1] = (short)f2bf(a.y);
    o[2] = (short)f2bf(a.z); o[3] = (short)f2bf(a.w);
    o[4] = (short)f2bf(b.x); o[5] = (short)f2bf(b.y);
    o[6] = (short)f2bf(b.z); o[7] = (short)f2bf(b.w);
    return o;
}

// ---------------------------------------------------------------------------
// Pass 1: one block per graph.
//  - converts its 16-element slice of W1 to bf16 (replaces the old k_wcvt)
//  - binary-search segment bounds in sorted batch_id
//  - streams the segment: fp32 sums for the mean AND (if WXB) writes the rows
//    back as bf16 into xb (coalesced 8B/lane stores)
//  - ctx[g] = mean @ W2^T + b
// ---------------------------------------------------------------------------
template <bool WXB>
__global__ __launch_bounds__(256) void k_pass1(
        const float* __restrict__ x, const int* __restrict__ bid,
        const float* __restrict__ W, const float* __restrict__ b,
        float* __restrict__ ctx, unsigned short* __restrict__ W1b,
        unsigned short* __restrict__ xb, int N) {
    int g = blockIdx.x;
    int tid = threadIdx.x;

    // W1 -> bf16, 16384 elems spread over 1024 blocks (16 each)
    if (tid < 16) {
        int i = (g << 4) + tid;
        W1b[i] = f2bf(W[(i >> 7) * 256 + (i & 127)]);
    }

    int lo = 0, hi = N;
    while (lo < hi) { int m = (lo + hi) >> 1; if (bid[m] < g) lo = m + 1; else hi = m; }
    int start = lo;
    int lo2 = start, hi2 = N;
    while (lo2 < hi2) { int m = (lo2 + hi2) >> 1; if (bid[m] < g + 1) lo2 = m + 1; else hi2 = m; }
    int end = lo2;
    int cnt = end - start;

    __shared__ float4 red[8][32];
    __shared__ float ms[IN_F];

    int c4 = tid & 31;      // float4 column
    int rg = tid >> 5;      // row stripe 0..7
    float4 s0 = make_float4(0.f, 0.f, 0.f, 0.f);
    float4 s1 = s0, s2 = s0, s3 = s0;

    int r = start + rg;
    for (; r + 24 < end; r += 32) {
        float4 a = *(const float4*)(x + (size_t)(r     ) * IN_F + c4 * 4);
        float4 c = *(const float4*)(x + (size_t)(r +  8) * IN_F + c4 * 4);
        float4 d = *(const float4*)(x + (size_t)(r + 16) * IN_F + c4 * 4);
        float4 e = *(const float4*)(x + (size_t)(r + 24) * IN_F + c4 * 4);
        if (WXB) {
            *(us4*)(xb + (size_t)(r     ) * IN_F + c4 * 4) = pack4(a);
            *(us4*)(xb + (size_t)(r +  8) * IN_F + c4 * 4) = pack4(c);
            *(us4*)(xb + (size_t)(r + 16) * IN_F + c4 * 4) = pack4(d);
            *(us4*)(xb + (size_t)(r + 24) * IN_F + c4 * 4) = pack4(e);
        }
        s0.x += a.x; s0.y += a.y; s0.z += a.z; s0.w += a.w;
        s1.x += c.x; s1.y += c.y; s1.z += c.z; s1.w += c.w;
        s2.x += d.x; s2.y += d.y; s2.z += d.z; s2.w += d.w;
        s3.x += e.x; s3.y += e.y; s3.z += e.z; s3.w += e.w;
    }
    for (; r < end; r += 8) {
        float4 a = *(const float4*)(x + (size_t)r * IN_F + c4 * 4);
        if (WXB) *(us4*)(xb + (size_t)r * IN_F + c4 * 4) = pack4(a);
        s0.x += a.x; s0.y += a.y; s0.z += a.z; s0.w += a.w;
    }
    s0.x += s1.x + s2.x + s3.x;
    s0.y += s1.y + s2.y + s3.y;
    s0.z += s1.z + s2.z + s3.z;
    s0.w += s1.w + s2.w + s3.w;

    red[rg][c4] = s0;
    __syncthreads();
    if (tid < 32) {
        float4 t = red[0][tid];
        #pragma unroll
        for (int i = 1; i < 8; ++i) {
            float4 v = red[i][tid];
            t.x += v.x; t.y += v.y; t.z += v.z; t.w += v.w;
        }
        float inv = 1.0f / (float)(cnt > 0 ? cnt : 1);
        ms[tid * 4 + 0] = t.x * inv;
        ms[tid * 4 + 1] = t.y * inv;
        ms[tid * 4 + 2] = t.z * inv;
        ms[tid * 4 + 3] = t.w * inv;
    }
    __syncthreads();
    if (tid < OUT_F) {
        int o = tid;
        float acc = b[o];
        const float* w2 = W + o * 256 + 128;    // W2 row (L2 cached)
        #pragma unroll 8
        for (int k = 0; k < IN_F; ++k) acc += ms[k] * w2[k];
        ctx[g * OUT_F + o] = acc;
    }
}

// ---------------------------------------------------------------------------
// GEMM, bf16-A path: out[n][o] = sum_k xb[n][k]*W1b[o][k] + ctx[bid[n]][o]
// LDS-free, barrier-free. 128-row block tile; wave w owns rows [w*32, w*32+32)
// x all 128 output cols (2 mt x 8 ot of 16x16) -> no duplicated A reads.
// A loads are straight dwordx4 of bf16 (no conversion VALU). 3 blocks/CU.
// ---------------------------------------------------------------------------
__global__ __launch_bounds__(256, 3) void k_gemm_bf(
        const unsigned short* __restrict__ xb, const int* __restrict__ bid,
        const unsigned short* __restrict__ W1b, const float* __restrict__ ctx,
        float* __restrict__ out, int N) {
    int tid = threadIdx.x;
    int row0 = blockIdx.x * 128;
    int lane = tid & 63, wave = tid >> 6;
    int l16 = lane & 15, quad = lane >> 4;
    int wrow = wave * 32;

    f32x4 acc[2][8];
    #pragma unroll
    for (int mt = 0; mt < 2; ++mt)
        #pragma unroll
        for (int ot = 0; ot < 8; ++ot)
            acc[mt][ot] = (f32x4){0.f, 0.f, 0.f, 0.f};

    #pragma unroll
    for (int kt = 0; kt < 4; ++kt) {
        // A frags: lane holds row m=l16 (within 16-tile), k=quad*8+j
        short8 af[2];
        #pragma unroll
        for (int mt = 0; mt < 2; ++mt) {
            int rrow = row0 + wrow + mt * 16 + l16;
            short8 v = (short8){0, 0, 0, 0, 0, 0, 0, 0};
            if (rrow < N)
                v = *(const short8*)(xb + (size_t)rrow * IN_F + kt * 32 + quad * 8);
            af[mt] = v;
        }
        // B frags: lane holds col n=l16, k=quad*8+j  (W1b is 32KB, L1/L2-hot)
        #pragma unroll
        for (int ot = 0; ot < 8; ++ot) {
            short8 bf = *(const short8*)(W1b + (ot * 16 + l16) * IN_F + kt * 32 + quad * 8);
            acc[0][ot] = __builtin_amdgcn_mfma_f32_16x16x32_bf16(af[0], bf, acc[0][ot], 0, 0, 0);
            acc[1][ot] = __builtin_amdgcn_mfma_f32_16x16x32_bf16(af[1], bf, acc[1][ot], 0, 0, 0);
        }
    }

    // --- epilogue: D[row=quad*4+r4][col=l16] per 16x16 tile ---
    int lastrow = row0 + 127 < N ? row0 + 127 : N - 1;
    int b_lo = bid[row0], b_hi = bid[lastrow];
    if (b_lo == b_hi) {
        // whole tile in one graph (~74% of tiles): one ctx row
        float cv[8];
        #pragma unroll
        for (int ot = 0; ot < 8; ++ot)
            cv[ot] = ctx[b_lo * OUT_F + ot * 16 + l16];
        #pragma unroll
        for (int mt = 0; mt < 2; ++mt) {
            #pragma unroll
            for (int r4 = 0; r4 < 4; ++r4) {
                int row = row0 + wrow + mt * 16 + quad * 4 + r4;
                if (row < N) {
                    #pragma unroll
                    for (int ot = 0; ot < 8; ++ot)
                        out[(size_t)row * OUT_F + ot * 16 + l16] =
                            acc[mt][ot][r4] + cv[ot];
                }
            }
        }
    } else {
        #pragma unroll
        for (int mt = 0; mt < 2; ++mt) {
            #pragma unroll
            for (int r4 = 0; r4 < 4; ++r4) {
                int row = row0 + wrow + mt * 16 + quad * 4 + r4;
                if (row < N) {
                    int cb = bid[row] * OUT_F;
                    #pragma unroll
                    for (int ot = 0; ot < 8; ++ot)
                        out[(size_t)row * OUT_F + ot * 16 + l16] =
                            acc[mt][ot][r4] + ctx[cb + ot * 16 + l16];
                }
            }
        }
    }
}

// ---------------------------------------------------------------------------
// Fallback GEMM (fp32 A, in-register bf16 pack) — the previously verified
// kernel, used only if the workspace can't hold the bf16 staging buffer.
// ---------------------------------------------------------------------------
__global__ __launch_bounds__(256, 2) void k_gemm_f32(
        const float* __restrict__ x, const int* __restrict__ bid,
        const unsigned short* __restrict__ W1b, const float* __restrict__ ctx,
        float* __restrict__ out, int N) {
    int tid = threadIdx.x;
    int row0 = blockIdx.x * 128;
    int lane = tid & 63, wave = tid >> 6;
    int l16 = lane & 15, quad = lane >> 4;
    int wrow = (wave & 1) * 64;
    int wcol = (wave >> 1) * 64;

    f32x4 acc[4][4];
    #pragma unroll
    for (int mt = 0; mt < 4; ++mt)
        #pragma unroll
        for (int ot = 0; ot < 4; ++ot)
            acc[mt][ot] = (f32x4){0.f, 0.f, 0.f, 0.f};

    #pragma unroll
    for (int kt = 0; kt < 4; ++kt) {
        short8 bf[4];
        #pragma unroll
        for (int ot = 0; ot < 4; ++ot)
            bf[ot] = *(const short8*)(W1b + (wcol + ot * 16 + l16) * IN_F + kt * 32 + quad * 8);
        short8 af[4];
        #pragma unroll
        for (int mt = 0; mt < 4; ++mt) {
            int r = row0 + wrow + mt * 16 + l16;
            float4 v0 = make_float4(0.f, 0.f, 0.f, 0.f), v1 = v0;
            if (r < N) {
                const float* p = x + (size_t)r * IN_F + kt * 32 + quad * 8;
                v0 = *(const float4*)p;
                v1 = *(const float4*)(p + 4);
            }
            af[mt] = pack8(v0, v1);
        }
        #pragma unroll
        for (int mt = 0; mt < 4; ++mt)
            #pragma unroll
            for (int ot = 0; ot < 4; ++ot)
                acc[mt][ot] = __builtin_amdgcn_mfma_f32_16x16x32_bf16(
                    af[mt], bf[ot], acc[mt][ot], 0, 0, 0);
    }

    int lastrow = row0 + 127 < N ? row0 + 127 : N - 1;
    int b_lo = bid[row0], b_hi = bid[lastrow];
    if (b_lo == b_hi) {
        float cv[4];
        #pragma unroll
        for (int ot = 0; ot < 4; ++ot)
            cv[ot] = ctx[b_lo * OUT_F + wcol + ot * 16 + l16];
        #pragma unroll
        for (int mt = 0; mt < 4; ++mt) {
            #pragma unroll
            for (int r4 = 0; r4 < 4; ++r4) {
                int row = row0 + wrow + mt * 16 + quad * 4 + r4;
                if (row < N) {
                    #pragma unroll
                    for (int ot = 0; ot < 4; ++ot)
                        out[(size_t)row * OUT_F + wcol + ot * 16 + l16] =
                            acc[mt][ot][r4] + cv[ot];
                }
            }
        }
    } else {
        #pragma unroll
        for (int mt = 0; mt < 4; ++mt) {
            #pragma unroll
            for (int r4 = 0; r4 < 4; ++r4) {
                int row = row0 + wrow + mt * 16 + quad * 4 + r4;
                if (row < N) {
                    int cb = bid[row] * OUT_F;
                    #pragma unroll
                    for (int ot = 0; ot < 4; ++ot)
                        out[(size_t)row * OUT_F + wcol + ot * 16 + l16] =
                            acc[mt][ot][r4] + ctx[cb + wcol + ot * 16 + l16];
                }
            }
        }
    }
}

// ---------------------------------------------------------------------------
extern "C" void kernel_launch(void* const* d_in, const int* in_sizes, int n_in,
                              void* d_out, int out_size, void* d_ws, size_t ws_size,
                              hipStream_t stream) {
    const float* x  = (const float*)d_in[0];
    const int* bid  = (const int*)d_in[1];
    const float* W  = (const float*)d_in[2];
    const float* b  = (const float*)d_in[3];
    float* out      = (float*)d_out;
    int N = in_sizes[1];

    // workspace layout: ctx [1024*128 f32] | W1b [128*128 bf16] | xb [N*128 bf16]
    size_t ctx_bytes = (size_t)G_NUM * OUT_F * sizeof(float);
    size_t w1b_bytes = (size_t)OUT_F * IN_F * sizeof(unsigned short);
    float* ctx = (float*)d_ws;
    unsigned short* W1b = (unsigned short*)((char*)d_ws + ctx_bytes);
    unsigned short* xb  = (unsigned short*)((char*)d_ws + ctx_bytes + w1b_bytes);
    size_t need = ctx_bytes + w1b_bytes + (size_t)N * IN_F * sizeof(unsigned short);

    if (ws_size >= need) {
        k_pass1<true><<<G_NUM, 256, 0, stream>>>(x, bid, W, b, ctx, W1b, xb, N);
        k_gemm_bf<<<(N + 127) / 128, 256, 0, stream>>>(xb, bid, W1b, ctx, out, N);
    } else {
        k_pass1<false><<<G_NUM, 256, 0, stream>>>(x, bid, W, b, ctx, W1b, nullptr, N);
        k_gemm_f32<<<(N + 127) / 128, 256, 0, stream>>>(x, bid, W1b, ctx, out, N);
    }
}

// Round 2
// 511.547 us; speedup vs baseline: 1.0723x; 1.0575x over previous
//
#include <hip/hip_runtime.h>

// Problem: out[n,:] = concat(x[n,:], mean[batch_id[n],:]) @ W^T + b
//   N ~= 500000, IN = OUT = 128, G = 1024 graphs, batch_id SORTED.
// Fully-fused design: one block per graph. out[n] depends only on x[n] and
// its own graph's mean, so a block is self-contained:
//   phase B: stream segment rows (fp32), accumulate sums, stage rows as bf16
//            into LDS (XOR-swizzled 16B granules, row stride 256B)
//   phase C: reduce -> mean; ctx[g] = mean @ W2^T + b (kept in LDS)
//   phase D: out[rows] = LDS_A @ W1^T + ctx, W1 held as bf16 in registers.
// Traffic: read x ONCE (256 MB) + write out (256 MB) = the 512 MB floor.

#define G_NUM 1024
#define IN_F 128
#define OUT_F 128
#define CAP 616                              // staged rows per graph (5+ sigma above mean 488)
#define SMEM_BYTES (5120 + CAP * 256)        // 162816 <= 163840

typedef __attribute__((ext_vector_type(8))) short short8;          // 8 bf16
typedef __attribute__((ext_vector_type(4))) float f32x4;           // MFMA C/D frag
typedef __attribute__((ext_vector_type(4))) unsigned short us4;    // 4 bf16 = 8B

static __device__ __forceinline__ unsigned short f2bf(float f) {
    union { float f; unsigned u; } v; v.f = f;
    unsigned u = v.u;
    return (unsigned short)((u + 0x7FFFu + ((u >> 16) & 1u)) >> 16);  // RNE
}

static __device__ __forceinline__ us4 pack4(float4 a) {
    us4 o;
    o[0] = f2bf(a.x); o[1] = f2bf(a.y); o[2] = f2bf(a.z); o[3] = f2bf(a.w);
    return o;
}

static __device__ __forceinline__ short8 pack8(float4 a, float4 b) {
    short8 o;
    o[0] = (short)f2bf(a.x); o[1] = (short)f2bf(a.y);
    o[2] = (short)f2bf(a.z); o[3] = (short)f2bf(a.w);
    o[4] = (short)f2bf(b.x); o[5] = (short)f2bf(b.y);
    o[6] = (short)f2bf(b.z); o[7] = (short)f2bf(b.w);
    return o;
}

// ---------------------------------------------------------------------------
// Fused kernel: one block per graph, 256 threads, dynamic LDS.
// ---------------------------------------------------------------------------
__global__ __launch_bounds__(256, 1) void k_fused(
        const float* __restrict__ x, const int* __restrict__ bid,
        const float* __restrict__ W, const float* __restrict__ b,
        float* __restrict__ out, int N) {
    extern __shared__ char smem[];
    float4 (*red)[32] = (float4 (*)[32])(smem);      // 8*32*16 = 4096 B
    float* ms   = (float*)(smem + 4096);             // 128 f32 mean
    float* ctxs = (float*)(smem + 4608);             // 128 f32 ctx row
    char* xs    = smem + 5120;                       // CAP rows x 256 B (bf16, swizzled)

    int g = blockIdx.x;
    int tid = threadIdx.x;

    // segment bounds in sorted batch_id
    int lo = 0, hi = N;
    while (lo < hi) { int m = (lo + hi) >> 1; if (bid[m] < g) lo = m + 1; else hi = m; }
    int start = lo;
    int lo2 = start, hi2 = N;
    while (lo2 < hi2) { int m = (lo2 + hi2) >> 1; if (bid[m] < g + 1) lo2 = m + 1; else hi2 = m; }
    int end = lo2;
    int cnt = end - start;

    // ---- phase B: stream rows, fp32 sums + bf16 LDS staging ----
    int c4 = tid & 31;          // 16B (fp32 float4) column 0..31
    int rg = tid >> 5;          // row stripe 0..7
    int uu = c4 >> 1;           // 16B bf16 granule 0..15 within row
    int hb = (c4 & 1) * 8;      // byte offset within granule
    float4 s0 = make_float4(0.f, 0.f, 0.f, 0.f);
    float4 s1 = s0, s2 = s0, s3 = s0;

    int r = start + rg;
    for (; r + 24 < end; r += 32) {
        const float* p0 = x + (size_t)r * IN_F + c4 * 4;
        float4 a = *(const float4*)(p0);
        float4 c = *(const float4*)(p0 +  8 * IN_F);
        float4 d = *(const float4*)(p0 + 16 * IN_F);
        float4 e = *(const float4*)(p0 + 24 * IN_F);
        int lr = r - start;
        int sw = ((uu ^ (lr & 7)) << 4) + hb;   // rows lr,lr+8,.. share lr&7
        if (lr      < CAP) *(us4*)(xs + (size_t)(lr     ) * 256 + sw) = pack4(a);
        if (lr +  8 < CAP) *(us4*)(xs + (size_t)(lr +  8) * 256 + sw) = pack4(c);
        if (lr + 16 < CAP) *(us4*)(xs + (size_t)(lr + 16) * 256 + sw) = pack4(d);
        if (lr + 24 < CAP) *(us4*)(xs + (size_t)(lr + 24) * 256 + sw) = pack4(e);
        s0.x += a.x; s0.y += a.y; s0.z += a.z; s0.w += a.w;
        s1.x += c.x; s1.y += c.y; s1.z += c.z; s1.w += c.w;
        s2.x += d.x; s2.y += d.y; s2.z += d.z; s2.w += d.w;
        s3.x += e.x; s3.y += e.y; s3.z += e.z; s3.w += e.w;
    }
    for (; r < end; r += 8) {
        float4 a = *(const float4*)(x + (size_t)r * IN_F + c4 * 4);
        int lr = r - start;
        if (lr < CAP) *(us4*)(xs + (size_t)lr * 256 + ((uu ^ (lr & 7)) << 4) + hb) = pack4(a);
        s0.x += a.x; s0.y += a.y; s0.z += a.z; s0.w += a.w;
    }
    s0.x += s1.x + s2.x + s3.x;
    s0.y += s1.y + s2.y + s3.y;
    s0.z += s1.z + s2.z + s3.z;
    s0.w += s1.w + s2.w + s3.w;

    red[rg][c4] = s0;
    __syncthreads();

    int lane = tid & 63, wave = tid >> 6;
    int l16 = lane & 15, quad = lane >> 4;

    // ---- W1 -> bf16 register fragments (held across phase D) ----
    // lane needs W1[ot*16+l16][kt*32+quad*8 .. +8]; W is L3-hot after first blocks.
    short8 bw[4][8];
    #pragma unroll
    for (int kt = 0; kt < 4; ++kt)
        #pragma unroll
        for (int ot = 0; ot < 8; ++ot) {
            const float* wp = W + (size_t)(ot * 16 + l16) * 256 + kt * 32 + quad * 8;
            bw[kt][ot] = pack8(*(const float4*)wp, *(const float4*)(wp + 4));
        }

    // ---- phase C: reduce -> mean; ctx = mean @ W2^T + b ----
    if (tid < 32) {
        float4 t = red[0][tid];
        #pragma unroll
        for (int i = 1; i < 8; ++i) {
            float4 v = red[i][tid];
            t.x += v.x; t.y += v.y; t.z += v.z; t.w += v.w;
        }
        float inv = 1.0f / (float)(cnt > 0 ? cnt : 1);
        ms[tid * 4 + 0] = t.x * inv;
        ms[tid * 4 + 1] = t.y * inv;
        ms[tid * 4 + 2] = t.z * inv;
        ms[tid * 4 + 3] = t.w * inv;
    }
    __syncthreads();
    if (tid < OUT_F) {
        float acc = b[tid];
        const float* w2 = W + (size_t)tid * 256 + 128;
        #pragma unroll 8
        for (int k = 0; k < IN_F; ++k) acc += ms[k] * w2[k];
        ctxs[tid] = acc;
    }
    __syncthreads();

    // ---- phase D: out[rows] = A(LDS bf16) @ W1^T(regs) + ctx ----
    float cv[8];
    #pragma unroll
    for (int ot = 0; ot < 8; ++ot) cv[ot] = ctxs[ot * 16 + l16];

    int ntiles = (cnt + 15) >> 4;
    for (int t = wave; t < ntiles; t += 4) {
        int lr = t * 16 + l16;
        short8 af[4];
        if (lr < cnt && lr < CAP) {
            const char* rp = xs + (size_t)lr * 256;
            int swb = lr & 7;
            #pragma unroll
            for (int kt = 0; kt < 4; ++kt)
                af[kt] = *(const short8*)(rp + (((kt * 4 + quad) ^ swb) << 4));
        } else if (lr < cnt) {
            // spill rows beyond CAP (statistically never): re-read from global
            const float* p = x + (size_t)(start + lr) * IN_F;
            #pragma unroll
            for (int kt = 0; kt < 4; ++kt)
                af[kt] = pack8(*(const float4*)(p + kt * 32 + quad * 8),
                               *(const float4*)(p + kt * 32 + quad * 8 + 4));
        } else {
            #pragma unroll
            for (int kt = 0; kt < 4; ++kt) af[kt] = (short8){0, 0, 0, 0, 0, 0, 0, 0};
        }

        f32x4 acc[8];
        #pragma unroll
        for (int ot = 0; ot < 8; ++ot) acc[ot] = (f32x4){0.f, 0.f, 0.f, 0.f};
        #pragma unroll
        for (int kt = 0; kt < 4; ++kt)
            #pragma unroll
            for (int ot = 0; ot < 8; ++ot)
                acc[ot] = __builtin_amdgcn_mfma_f32_16x16x32_bf16(
                    af[kt], bw[kt][ot], acc[ot], 0, 0, 0);

        #pragma unroll
        for (int r4 = 0; r4 < 4; ++r4) {
            int rl = t * 16 + quad * 4 + r4;
            if (rl < cnt) {
                float* po = out + (size_t)(start + rl) * OUT_F;
                #pragma unroll
                for (int ot = 0; ot < 8; ++ot)
                    po[ot * 16 + l16] = acc[ot][r4] + cv[ot];
            }
        }
    }
}

// ===========================================================================
// Fallback path (round-1 verified): pass1 + bf16 GEMM, used only if the
// dynamic-LDS opt-in fails.
// ===========================================================================
template <bool WXB>
__global__ __launch_bounds__(256) void k_pass1(
        const float* __restrict__ x, const int* __restrict__ bid,
        const float* __restrict__ W, const float* __restrict__ b,
        float* __restrict__ ctx, unsigned short* __restrict__ W1b,
        unsigned short* __restrict__ xb, int N) {
    int g = blockIdx.x;
    int tid = threadIdx.x;

    if (tid < 16) {
        int i = (g << 4) + tid;
        W1b[i] = f2bf(W[(i >> 7) * 256 + (i & 127)]);
    }

    int lo = 0, hi = N;
    while (lo < hi) { int m = (lo + hi) >> 1; if (bid[m] < g) lo = m + 1; else hi = m; }
    int start = lo;
    int lo2 = start, hi2 = N;
    while (lo2 < hi2) { int m = (lo2 + hi2) >> 1; if (bid[m] < g + 1) lo2 = m + 1; else hi2 = m; }
    int end = lo2;
    int cnt = end - start;

    __shared__ float4 red[8][32];
    __shared__ float ms[IN_F];

    int c4 = tid & 31;
    int rg = tid >> 5;
    float4 s0 = make_float4(0.f, 0.f, 0.f, 0.f);
    float4 s1 = s0, s2 = s0, s3 = s0;

    int r = start + rg;
    for (; r + 24 < end; r += 32) {
        float4 a = *(const float4*)(x + (size_t)(r     ) * IN_F + c4 * 4);
        float4 c = *(const float4*)(x + (size_t)(r +  8) * IN_F + c4 * 4);
        float4 d = *(const float4*)(x + (size_t)(r + 16) * IN_F + c4 * 4);
        float4 e = *(const float4*)(x + (size_t)(r + 24) * IN_F + c4 * 4);
        if (WXB) {
            *(us4*)(xb + (size_t)(r     ) * IN_F + c4 * 4) = pack4(a);
            *(us4*)(xb + (size_t)(r +  8) * IN_F + c4 * 4) = pack4(c);
            *(us4*)(xb + (size_t)(r + 16) * IN_F + c4 * 4) = pack4(d);
            *(us4*)(xb + (size_t)(r + 24) * IN_F + c4 * 4) = pack4(e);
        }
        s0.x += a.x; s0.y += a.y; s0.z += a.z; s0.w += a.w;
        s1.x += c.x; s1.y += c.y; s1.z += c.z; s1.w += c.w;
        s2.x += d.x; s2.y += d.y; s2.z += d.z; s2.w += d.w;
        s3.x += e.x; s3.y += e.y; s3.z += e.z; s3.w += e.w;
    }
    for (; r < end; r += 8) {
        float4 a = *(const float4*)(x + (size_t)r * IN_F + c4 * 4);
        if (WXB) *(us4*)(xb + (size_t)r * IN_F + c4 * 4) = pack4(a);
        s0.x += a.x; s0.y += a.y; s0.z += a.z; s0.w += a.w;
    }
    s0.x += s1.x + s2.x + s3.x;
    s0.y += s1.y + s2.y + s3.y;
    s0.z += s1.z + s2.z + s3.z;
    s0.w += s1.w + s2.w + s3.w;

    red[rg][c4] = s0;
    __syncthreads();
    if (tid < 32) {
        float4 t = red[0][tid];
        #pragma unroll
        for (int i = 1; i < 8; ++i) {
            float4 v = red[i][tid];
            t.x += v.x; t.y += v.y; t.z += v.z; t.w += v.w;
        }
        float inv = 1.0f / (float)(cnt > 0 ? cnt : 1);
        ms[tid * 4 + 0] = t.x * inv;
        ms[tid * 4 + 1] = t.y * inv;
        ms[tid * 4 + 2] = t.z * inv;
        ms[tid * 4 + 3] = t.w * inv;
    }
    __syncthreads();
    if (tid < OUT_F) {
        int o = tid;
        float acc = b[o];
        const float* w2 = W + o * 256 + 128;
        #pragma unroll 8
        for (int k = 0; k < IN_F; ++k) acc += ms[k] * w2[k];
        ctx[g * OUT_F + o] = acc;
    }
}

__global__ __launch_bounds__(256, 3) void k_gemm_bf(
        const unsigned short* __restrict__ xb, const int* __restrict__ bid,
        const unsigned short* __restrict__ W1b, const float* __restrict__ ctx,
        float* __restrict__ out, int N) {
    int tid = threadIdx.x;
    int row0 = blockIdx.x * 128;
    int lane = tid & 63, wave = tid >> 6;
    int l16 = lane & 15, quad = lane >> 4;
    int wrow = wave * 32;

    f32x4 acc[2][8];
    #pragma unroll
    for (int mt = 0; mt < 2; ++mt)
        #pragma unroll
        for (int ot = 0; ot < 8; ++ot)
            acc[mt][ot] = (f32x4){0.f, 0.f, 0.f, 0.f};

    #pragma unroll
    for (int kt = 0; kt < 4; ++kt) {
        short8 af[2];
        #pragma unroll
        for (int mt = 0; mt < 2; ++mt) {
            int rrow = row0 + wrow + mt * 16 + l16;
            short8 v = (short8){0, 0, 0, 0, 0, 0, 0, 0};
            if (rrow < N)
                v = *(const short8*)(xb + (size_t)rrow * IN_F + kt * 32 + quad * 8);
            af[mt] = v;
        }
        #pragma unroll
        for (int ot = 0; ot < 8; ++ot) {
            short8 bf = *(const short8*)(W1b + (ot * 16 + l16) * IN_F + kt * 32 + quad * 8);
            acc[0][ot] = __builtin_amdgcn_mfma_f32_16x16x32_bf16(af[0], bf, acc[0][ot], 0, 0, 0);
            acc[1][ot] = __builtin_amdgcn_mfma_f32_16x16x32_bf16(af[1], bf, acc[1][ot], 0, 0, 0);
        }
    }

    int lastrow = row0 + 127 < N ? row0 + 127 : N - 1;
    int b_lo = bid[row0], b_hi = bid[lastrow];
    if (b_lo == b_hi) {
        float cv[8];
        #pragma unroll
        for (int ot = 0; ot < 8; ++ot)
            cv[ot] = ctx[b_lo * OUT_F + ot * 16 + l16];
        #pragma unroll
        for (int mt = 0; mt < 2; ++mt) {
            #pragma unroll
            for (int r4 = 0; r4 < 4; ++r4) {
                int row = row0 + wrow + mt * 16 + quad * 4 + r4;
                if (row < N) {
                    #pragma unroll
                    for (int ot = 0; ot < 8; ++ot)
                        out[(size_t)row * OUT_F + ot * 16 + l16] =
                            acc[mt][ot][r4] + cv[ot];
                }
            }
        }
    } else {
        #pragma unroll
        for (int mt = 0; mt < 2; ++mt) {
            #pragma unroll
            for (int r4 = 0; r4 < 4; ++r4) {
                int row = row0 + wrow + mt * 16 + quad * 4 + r4;
                if (row < N) {
                    int cb = bid[row] * OUT_F;
                    #pragma unroll
                    for (int ot = 0; ot < 8; ++ot)
                        out[(size_t)row * OUT_F + ot * 16 + l16] =
                            acc[mt][ot][r4] + ctx[cb + ot * 16 + l16];
                }
            }
        }
    }
}

// ---------------------------------------------------------------------------
extern "C" void kernel_launch(void* const* d_in, const int* in_sizes, int n_in,
                              void* d_out, int out_size, void* d_ws, size_t ws_size,
                              hipStream_t stream) {
    const float* x  = (const float*)d_in[0];
    const int* bid  = (const int*)d_in[1];
    const float* W  = (const float*)d_in[2];
    const float* b  = (const float*)d_in[3];
    float* out      = (float*)d_out;
    int N = in_sizes[1];

    static int fused_ok = -1;
    if (fused_ok < 0) {
        fused_ok = (hipFuncSetAttribute(
                        reinterpret_cast<const void*>(&k_fused),
                        hipFuncAttributeMaxDynamicSharedMemorySize,
                        SMEM_BYTES) == hipSuccess) ? 1 : 0;
    }

    if (fused_ok) {
        k_fused<<<G_NUM, 256, SMEM_BYTES, stream>>>(x, bid, W, b, out, N);
        return;
    }

    // fallback: round-1 verified 2-kernel path (needs workspace)
    size_t ctx_bytes = (size_t)G_NUM * OUT_F * sizeof(float);
    size_t w1b_bytes = (size_t)OUT_F * IN_F * sizeof(unsigned short);
    float* ctx = (float*)d_ws;
    unsigned short* W1b = (unsigned short*)((char*)d_ws + ctx_bytes);
    unsigned short* xb  = (unsigned short*)((char*)d_ws + ctx_bytes + w1b_bytes);

    k_pass1<true><<<G_NUM, 256, 0, stream>>>(x, bid, W, b, ctx, W1b, xb, N);
    k_gemm_bf<<<(N + 127) / 128, 256, 0, stream>>>(xb, bid, W1b, ctx, out, N);
}